// Round 9
// baseline (704.910 us; speedup 1.0000x reference)
//
#include <hip/hip_runtime.h>

#define S_LEN 2048
#define D_MODEL 1024
#define N3 3072
#define NHEAD 16
#define DHEAD 64

typedef __attribute__((ext_vector_type(8))) short bf16x8;
typedef __attribute__((ext_vector_type(4))) float f32x4;

__device__ __forceinline__ unsigned short bf16_rne(float x) {
    unsigned int u = __float_as_uint(x);
    u += 0x7FFFu + ((u >> 16) & 1u);
    return (unsigned short)(u >> 16);
}
__device__ __forceinline__ float bf16_f(unsigned short h) {
    return __uint_as_float(((unsigned int)h) << 16);
}

// ============ GEMM-KQ: C[:, 0:2048] = inputs @ W[:, 0:2048] + b, stored split ============
// (reverted to R4's separate-kernel form: measured faster than the merged variant)
__global__ __launch_bounds__(256) void gemm_kq(
        const float* __restrict__ A, const float* __restrict__ Wm,
        const float* __restrict__ bias,
        unsigned short* __restrict__ khi, unsigned short* __restrict__ klo) {
    __shared__ unsigned short Ash[128*36], Asl[128*36], Bth[128*36], Btl[128*36];
    const int tid = threadIdx.x;
    const int n0 = blockIdx.x * 128;
    const int m0 = blockIdx.y * 128;
    const int lane = tid & 63, wid = tid >> 6;
    const int wm = wid >> 1, wn = wid & 1;
    const int lr = lane & 15, lc = lane >> 4;
    const int ar = tid >> 1, akc = (tid & 1) * 16;
    const int bk2 = (tid & 15) * 2, bnc = (tid >> 4) * 8;

    f32x4 acc[4][4];
    #pragma unroll
    for (int i = 0; i < 4; ++i)
        #pragma unroll
        for (int j = 0; j < 4; ++j) acc[i][j] = (f32x4){0.f, 0.f, 0.f, 0.f};

    for (int k0 = 0; k0 < D_MODEL; k0 += 32) {
        const float* ap = A + (size_t)(m0 + ar) * D_MODEL + k0 + akc;
        float4 a0 = *(const float4*)(ap);
        float4 a1 = *(const float4*)(ap + 4);
        float4 a2 = *(const float4*)(ap + 8);
        float4 a3 = *(const float4*)(ap + 12);
        const float* wp0 = Wm + (size_t)(k0 + bk2) * N3 + n0 + bnc;
        const float* wp1 = wp0 + N3;
        float4 w00 = *(const float4*)(wp0), w01 = *(const float4*)(wp0 + 4);
        float4 w10 = *(const float4*)(wp1), w11 = *(const float4*)(wp1 + 4);
        __syncthreads();
        {
            float af[16] = {a0.x,a0.y,a0.z,a0.w, a1.x,a1.y,a1.z,a1.w,
                            a2.x,a2.y,a2.z,a2.w, a3.x,a3.y,a3.z,a3.w};
            unsigned short hs[16], ls[16];
            #pragma unroll
            for (int i = 0; i < 16; ++i) {
                hs[i] = bf16_rne(af[i]);
                ls[i] = bf16_rne(af[i] - bf16_f(hs[i]));
            }
            #pragma unroll
            for (int i = 0; i < 16; i += 4) {
                *(ushort4*)&Ash[ar*36 + akc + i] = make_ushort4(hs[i],hs[i+1],hs[i+2],hs[i+3]);
                *(ushort4*)&Asl[ar*36 + akc + i] = make_ushort4(ls[i],ls[i+1],ls[i+2],ls[i+3]);
            }
            float r0[8] = {w00.x,w00.y,w00.z,w00.w, w01.x,w01.y,w01.z,w01.w};
            float r1[8] = {w10.x,w10.y,w10.z,w10.w, w11.x,w11.y,w11.z,w11.w};
            #pragma unroll
            for (int i = 0; i < 8; ++i) {
                unsigned short h0 = bf16_rne(r0[i]), h1 = bf16_rne(r1[i]);
                unsigned short l0 = bf16_rne(r0[i] - bf16_f(h0));
                unsigned short l1 = bf16_rne(r1[i] - bf16_f(h1));
                *(ushort2*)&Bth[(bnc + i)*36 + bk2] = make_ushort2(h0, h1);
                *(ushort2*)&Btl[(bnc + i)*36 + bk2] = make_ushort2(l0, l1);
            }
        }
        __syncthreads();
        bf16x8 ah[4], al[4], bh[4], bl[4];
        #pragma unroll
        for (int i = 0; i < 4; ++i) {
            int ra = (wm*64 + i*16 + lr)*36 + lc*8;
            int rb = (wn*64 + i*16 + lr)*36 + lc*8;
            ah[i] = *(const bf16x8*)&Ash[ra];
            al[i] = *(const bf16x8*)&Asl[ra];
            bh[i] = *(const bf16x8*)&Bth[rb];
            bl[i] = *(const bf16x8*)&Btl[rb];
        }
        #pragma unroll
        for (int mi = 0; mi < 4; ++mi)
            #pragma unroll
            for (int ni = 0; ni < 4; ++ni) {
                acc[mi][ni] = __builtin_amdgcn_mfma_f32_16x16x32_bf16(ah[mi], bh[ni], acc[mi][ni], 0, 0, 0);
                acc[mi][ni] = __builtin_amdgcn_mfma_f32_16x16x32_bf16(ah[mi], bl[ni], acc[mi][ni], 0, 0, 0);
                acc[mi][ni] = __builtin_amdgcn_mfma_f32_16x16x32_bf16(al[mi], bh[ni], acc[mi][ni], 0, 0, 0);
            }
    }
    #pragma unroll
    for (int ni = 0; ni < 4; ++ni) {
        int n = n0 + wn*64 + ni*16 + lr;
        float bv = bias[n];
        #pragma unroll
        for (int mi = 0; mi < 4; ++mi)
            #pragma unroll
            for (int r = 0; r < 4; ++r) {
                int m = m0 + wm*64 + mi*16 + lc*4 + r;
                float x = acc[mi][ni][r] + bv;
                unsigned short h = bf16_rne(x);
                khi[(size_t)m*2048 + n] = h;
                klo[(size_t)m*2048 + n] = bf16_rne(x - bf16_f(h));
            }
    }
}

// ============ GEMM-V: vt[n-2048][s] = (inputs @ W[:, 2048:3072] + b)^T, stored split ============
__global__ __launch_bounds__(256) void gemm_v(
        const float* __restrict__ A, const float* __restrict__ Wm,
        const float* __restrict__ bias,
        unsigned short* __restrict__ vthi, unsigned short* __restrict__ vtlo) {
    __shared__ unsigned short Ash[128*36], Asl[128*36], Bth[128*36], Btl[128*36];
    const int tid = threadIdx.x;
    const int n0 = 2048 + blockIdx.x * 128;
    const int m0 = blockIdx.y * 128;
    const int lane = tid & 63, wid = tid >> 6;
    const int wm = wid >> 1, wn = wid & 1;
    const int lr = lane & 15, lc = lane >> 4;
    const int ar = tid >> 1, akc = (tid & 1) * 16;
    const int bk2 = (tid & 15) * 2, bnc = (tid >> 4) * 8;

    f32x4 acc[4][4];
    #pragma unroll
    for (int i = 0; i < 4; ++i)
        #pragma unroll
        for (int j = 0; j < 4; ++j) acc[i][j] = (f32x4){0.f, 0.f, 0.f, 0.f};

    for (int k0 = 0; k0 < D_MODEL; k0 += 32) {
        const float* ap = A + (size_t)(m0 + ar) * D_MODEL + k0 + akc;
        float4 a0 = *(const float4*)(ap);
        float4 a1 = *(const float4*)(ap + 4);
        float4 a2 = *(const float4*)(ap + 8);
        float4 a3 = *(const float4*)(ap + 12);
        const float* wp0 = Wm + (size_t)(k0 + bk2) * N3 + n0 + bnc;
        const float* wp1 = wp0 + N3;
        float4 w00 = *(const float4*)(wp0), w01 = *(const float4*)(wp0 + 4);
        float4 w10 = *(const float4*)(wp1), w11 = *(const float4*)(wp1 + 4);
        __syncthreads();
        {
            float af[16] = {a0.x,a0.y,a0.z,a0.w, a1.x,a1.y,a1.z,a1.w,
                            a2.x,a2.y,a2.z,a2.w, a3.x,a3.y,a3.z,a3.w};
            unsigned short hs[16], ls[16];
            #pragma unroll
            for (int i = 0; i < 16; ++i) {
                hs[i] = bf16_rne(af[i]);
                ls[i] = bf16_rne(af[i] - bf16_f(hs[i]));
            }
            #pragma unroll
            for (int i = 0; i < 16; i += 4) {
                *(ushort4*)&Ash[ar*36 + akc + i] = make_ushort4(hs[i],hs[i+1],hs[i+2],hs[i+3]);
                *(ushort4*)&Asl[ar*36 + akc + i] = make_ushort4(ls[i],ls[i+1],ls[i+2],ls[i+3]);
            }
            float r0[8] = {w00.x,w00.y,w00.z,w00.w, w01.x,w01.y,w01.z,w01.w};
            float r1[8] = {w10.x,w10.y,w10.z,w10.w, w11.x,w11.y,w11.z,w11.w};
            #pragma unroll
            for (int i = 0; i < 8; ++i) {
                unsigned short h0 = bf16_rne(r0[i]), h1 = bf16_rne(r1[i]);
                unsigned short l0 = bf16_rne(r0[i] - bf16_f(h0));
                unsigned short l1 = bf16_rne(r1[i] - bf16_f(h1));
                *(ushort2*)&Bth[(bnc + i)*36 + bk2] = make_ushort2(h0, h1);
                *(ushort2*)&Btl[(bnc + i)*36 + bk2] = make_ushort2(l0, l1);
            }
        }
        __syncthreads();
        bf16x8 nh[4], nl[4], sh[4], sl[4];
        #pragma unroll
        for (int i = 0; i < 4; ++i) {
            int rb = (wm*64 + i*16 + lr)*36 + lc*8;   // n-side from W^T tile
            int ra = (wn*64 + i*16 + lr)*36 + lc*8;   // s-side from inputs tile
            nh[i] = *(const bf16x8*)&Bth[rb];
            nl[i] = *(const bf16x8*)&Btl[rb];
            sh[i] = *(const bf16x8*)&Ash[ra];
            sl[i] = *(const bf16x8*)&Asl[ra];
        }
        #pragma unroll
        for (int mi = 0; mi < 4; ++mi)
            #pragma unroll
            for (int ni = 0; ni < 4; ++ni) {
                acc[mi][ni] = __builtin_amdgcn_mfma_f32_16x16x32_bf16(nh[mi], sh[ni], acc[mi][ni], 0, 0, 0);
                acc[mi][ni] = __builtin_amdgcn_mfma_f32_16x16x32_bf16(nh[mi], sl[ni], acc[mi][ni], 0, 0, 0);
                acc[mi][ni] = __builtin_amdgcn_mfma_f32_16x16x32_bf16(nl[mi], sh[ni], acc[mi][ni], 0, 0, 0);
            }
    }
    #pragma unroll
    for (int mi = 0; mi < 4; ++mi)
        #pragma unroll
        for (int r = 0; r < 4; ++r) {
            int nr = n0 + wm*64 + mi*16 + lc*4 + r;   // global col in [2048,3072)
            float bv = bias[nr];
            int vrow = nr - 2048;
            #pragma unroll
            for (int ni = 0; ni < 4; ++ni) {
                int sg = m0 + wn*64 + ni*16 + lr;
                float x = acc[mi][ni][r] + bv;
                unsigned short h = bf16_rne(x);
                vthi[(size_t)vrow*4096 + sg] = h;
                vtlo[(size_t)vrow*4096 + sg] = bf16_rne(x - bf16_f(h));
            }
        }
}

// ============ Fused attention, k-split across waves, low-LDS quarter epilogue ============
// Block = 256 thr / 4 waves, q-tile 64; each wave owns a 32-key slice of each
// 128-key tile. Swapped QK^T (A=K,B=Q); per-wave LDS bounce for the PV A-frag
// (no barriers in the k-loop). Epilogue reduces wave partials one 16-wide
// d-quarter at a time: per-wave quarter buffer (5120 B) exactly overlays the
// wave's own Wt region, so LDS = 20.5 KB -> 4 blocks/CU.
#define NT 16   // 2048 / 128
__global__ __launch_bounds__(256, 4) void attn_mfma(
        const unsigned short* __restrict__ khi, const unsigned short* __restrict__ klo,
        const unsigned short* __restrict__ vthi, const unsigned short* __restrict__ vtlo,
        const float* __restrict__ masks, float* __restrict__ out) {
    __shared__ char pool[4*5120];             // 20480 B: per-wave Wt (k-loop) / acc quarter (epilogue)
    __shared__ float denL[4][64];
    unsigned short* Wt = (unsigned short*)pool;   // wave region: wid*2560 ushorts, [q][k] stride 40
    float* accL = (float*)pool;                   // wave region: wid*1280 floats, [q][d] stride 20

    const int tid = threadIdx.x;
    const int lane = tid & 63, wid = tid >> 6;
    const int lr = lane & 15, lc = lane >> 4;

    const int bid = blockIdx.x;
    const int work = (bid & 7) * 128 + (bid >> 3);   // XCD swizzle (1024 % 8 == 0, bijective)
    const int qb = work & 31;
    const int h  = (work >> 5) & 15;
    const int b  = work >> 9;
    const int q0 = qb * 64;
    const size_t srow = (size_t)b * S_LEN;

    // Q fragments (B-operand): q = q0+ni*16+lr, d = ks*32+lc*8, held all kernel
    bf16x8 qh[4][2], ql[4][2];
    #pragma unroll
    for (int ni = 0; ni < 4; ++ni)
        #pragma unroll
        for (int ks = 0; ks < 2; ++ks) {
            size_t off = (srow + q0 + ni*16 + lr) * 2048 + 1024 + h*64 + ks*32 + lc*8;
            qh[ni][ks] = *(const bf16x8*)(khi + off);
            ql[ni][ks] = *(const bf16x8*)(klo + off);
        }

    f32x4 acc[4][4];   // [ni: q-block][nd: d-block]
    #pragma unroll
    for (int i = 0; i < 4; ++i)
        #pragma unroll
        for (int j = 0; j < 4; ++j) acc[i][j] = (f32x4){0.f, 0.f, 0.f, 0.f};
    float den[4] = {0.f, 0.f, 0.f, 0.f};

    // K A-frags: rows = t*128 + wid*32 + mi*16 + lr, d = ks*32 + lc*8
    bf16x8 kh[2][2], kl[2][2];
    #pragma unroll
    for (int mi = 0; mi < 2; ++mi)
        #pragma unroll
        for (int ks = 0; ks < 2; ++ks) {
            size_t off = (srow + wid*32 + mi*16 + lr) * 2048 + h*64 + ks*32 + lc*8;
            kh[mi][ks] = *(const bf16x8*)(khi + off);
            kl[mi][ks] = *(const bf16x8*)(klo + off);
        }

    const int wtbase = wid * 2560;   // ushort index of this wave's Wt region

    for (int t = 0; t < NT; ++t) {
        // ---- QK^T (swapped: A=K slice, B=Q): u[mi][ni] reg r -> q=ni*16+lr, k=wid*32+mi*16+lc*4+r
        f32x4 u[2][4];
        #pragma unroll
        for (int mi = 0; mi < 2; ++mi)
            #pragma unroll
            for (int ni = 0; ni < 4; ++ni) u[mi][ni] = (f32x4){0.f, 0.f, 0.f, 0.f};
        #pragma unroll
        for (int ks = 0; ks < 2; ++ks)
            #pragma unroll
            for (int mi = 0; mi < 2; ++mi)
                #pragma unroll
                for (int ni = 0; ni < 4; ++ni) {
                    u[mi][ni] = __builtin_amdgcn_mfma_f32_16x16x32_bf16(kh[mi][ks], qh[ni][ks], u[mi][ni], 0, 0, 0);
                    u[mi][ni] = __builtin_amdgcn_mfma_f32_16x16x32_bf16(kh[mi][ks], ql[ni][ks], u[mi][ni], 0, 0, 0);
                    u[mi][ni] = __builtin_amdgcn_mfma_f32_16x16x32_bf16(kl[mi][ks], qh[ni][ks], u[mi][ni], 0, 0, 0);
                }
        // ---- prefetch next tile's K into the same frags (consumed next iteration)
        {
            int tn = (t + 1 < NT) ? t + 1 : t;
            #pragma unroll
            for (int mi = 0; mi < 2; ++mi)
                #pragma unroll
                for (int ks = 0; ks < 2; ++ks) {
                    size_t off = (srow + tn*128 + wid*32 + mi*16 + lr) * 2048 + h*64 + ks*32 + lc*8;
                    kh[mi][ks] = *(const bf16x8*)(khi + off);
                    kl[mi][ks] = *(const bf16x8*)(klo + off);
                }
        }
        // ---- V loads (issued early; consumed after exp)
        bf16x8 vh[4], vl[4];
        #pragma unroll
        for (int nd = 0; nd < 4; ++nd) {
            size_t voff = (size_t)(h*64 + nd*16 + lr) * 4096 + srow + t*128 + wid*32 + lc*8;
            vh[nd] = *(const bf16x8*)(vthi + voff);
            vl[nd] = *(const bf16x8*)(vtlo + voff);
        }
        // ---- masks for this lane's keys: k = t*128 + wid*32 + mi*16 + lc*4 + r
        float4 mk[2];
        #pragma unroll
        for (int mi = 0; mi < 2; ++mi)
            mk[mi] = *(const float4*)&masks[b*S_LEN + t*128 + wid*32 + mi*16 + lc*4];
        // ---- exp(elu-clip), pack to bf16 pairs, per-wave LDS transpose, den accum
        #pragma unroll
        for (int mi = 0; mi < 2; ++mi) {
            float mks[4] = {mk[mi].x, mk[mi].y, mk[mi].z, mk[mi].w};
            #pragma unroll
            for (int ni = 0; ni < 4; ++ni) {
                #pragma unroll
                for (int p = 0; p < 2; ++p) {
                    float x0 = u[mi][ni][2*p],   x1 = u[mi][ni][2*p+1];
                    float e0 = __expf(fminf(x0, 0.f)), e1 = __expf(fminf(x1, 0.f));
                    float t0 = x0 > 0.f ? x0 : e0 - 1.f;
                    float t1 = x1 > 0.f ? x1 : e1 - 1.f;
                    t0 = fminf(t0, 10.f); t1 = fminf(t1, 10.f);
                    float w0 = __expf(t0) * mks[2*p];
                    float w1 = __expf(t1) * mks[2*p+1];
                    unsigned short b0 = bf16_rne(w0), b1 = bf16_rne(w1);
                    den[ni] += bf16_f(b0) + bf16_f(b1);
                    unsigned int packed = (unsigned int)b0 | ((unsigned int)b1 << 16);
                    // Wt[q][k]: q = ni*16+lr (stride 40), k = mi*16 + lc*4 + 2p
                    *(unsigned int*)&Wt[wtbase + (ni*16 + lr)*40 + mi*16 + lc*4 + 2*p] = packed;
                }
            }
        }
        // ---- PV: A = P[q=lr][k=lc*8..+8] from Wt, B = V frags; acc[ni][nd]
        #pragma unroll
        for (int ni = 0; ni < 4; ++ni) {
            bf16x8 pa = *(const bf16x8*)&Wt[wtbase + (ni*16 + lr)*40 + lc*8];
            #pragma unroll
            for (int nd = 0; nd < 4; ++nd) {
                acc[ni][nd] = __builtin_amdgcn_mfma_f32_16x16x32_bf16(pa, vh[nd], acc[ni][nd], 0, 0, 0);
                acc[ni][nd] = __builtin_amdgcn_mfma_f32_16x16x32_bf16(pa, vl[nd], acc[ni][nd], 0, 0, 0);
            }
        }
    }

    // ---- den: reduce across lc groups (same q, different k subsets)
    #pragma unroll
    for (int ni = 0; ni < 4; ++ni) {
        float d = den[ni];
        d += __shfl_xor(d, 16);
        d += __shfl_xor(d, 32);
        den[ni] = d;
    }
    if (lc == 0) {
        #pragma unroll
        for (int ni = 0; ni < 4; ++ni) denL[wid][ni*16 + lr] = den[ni];
    }
    // ---- quarter-wise cross-wave reduction: per-wave accL region overlays own Wt region
    const int q  = tid >> 2;            // 0..63
    const int dg = (tid & 3) * 4;       // 0,4,8,12 within the 16-wide quarter
    float scale = 0.f;
    float* my = accL + wid * 1280;      // [64][20] floats
    #pragma unroll
    for (int nd = 0; nd < 4; ++nd) {
        #pragma unroll
        for (int ni = 0; ni < 4; ++ni)
            #pragma unroll
            for (int r = 0; r < 4; ++r)
                my[(ni*16 + lc*4 + r)*20 + lr] = acc[ni][nd][r];
        __syncthreads();
        if (nd == 0) {
            float dsum = denL[0][q] + denL[1][q] + denL[2][q] + denL[3][q];
            scale = masks[b*S_LEN + q0 + q] / dsum;
        }
        float4 s0 = *(float4*)&accL[0*1280 + q*20 + dg];
        float4 s1 = *(float4*)&accL[1*1280 + q*20 + dg];
        float4 s2 = *(float4*)&accL[2*1280 + q*20 + dg];
        float4 s3 = *(float4*)&accL[3*1280 + q*20 + dg];
        float4 o = make_float4((s0.x+s1.x+s2.x+s3.x)*scale,
                               (s0.y+s1.y+s2.y+s3.y)*scale,
                               (s0.z+s1.z+s2.z+s3.z)*scale,
                               (s0.w+s1.w+s2.w+s3.w)*scale);
        *(float4*)&out[(srow + q0 + q)*D_MODEL + h*64 + nd*16 + dg] = o;
        __syncthreads();
    }
}

extern "C" void kernel_launch(void* const* d_in, const int* in_sizes, int n_in,
                              void* d_out, int out_size, void* d_ws, size_t ws_size,
                              hipStream_t stream) {
    (void)in_sizes; (void)n_in; (void)out_size; (void)ws_size;
    const float* inputs = (const float*)d_in[0];
    const float* masks  = (const float*)d_in[1];
    const float* Wm     = (const float*)d_in[2];
    const float* bias   = (const float*)d_in[3];
    float* outp = (float*)d_out;

    // ws layout (50,331,648 B, same footprint as validated R3/R4/R7):
    unsigned short* khi  = (unsigned short*)d_ws;
    unsigned short* klo  = khi + (size_t)4096*2048;
    unsigned short* vthi = klo + (size_t)4096*2048;
    unsigned short* vtlo = vthi + (size_t)1024*4096;

    gemm_kq<<<dim3(16, 32), 256, 0, stream>>>(inputs, Wm, bias, khi, klo);
    gemm_v <<<dim3(8, 32), 256, 0, stream>>>(inputs, Wm, bias, vthi, vtlo);
    attn_mfma<<<1024, 256, 0, stream>>>(khi, klo, vthi, vtlo, masks, outp);
}

// Round 11
// 349.066 us; speedup vs baseline: 2.0194x; 2.0194x over previous
//
#include <hip/hip_runtime.h>

#define S_LEN 2048
#define D_MODEL 1024
#define N3 3072
#define NHEAD 16
#define DHEAD 64

typedef __attribute__((ext_vector_type(8))) short bf16x8;
typedef __attribute__((ext_vector_type(4))) float f32x4;

__device__ __forceinline__ unsigned short bf16_rne(float x) {
    unsigned int u = __float_as_uint(x);
    u += 0x7FFFu + ((u >> 16) & 1u);
    return (unsigned short)(u >> 16);
}
__device__ __forceinline__ float bf16_f(unsigned short h) {
    return __uint_as_float(((unsigned int)h) << 16);
}

// ============ GEMM-KQ: C[:, 0:2048] = inputs @ W[:, 0:2048] + b, stored split ============
__global__ __launch_bounds__(256) void gemm_kq(
        const float* __restrict__ A, const float* __restrict__ Wm,
        const float* __restrict__ bias,
        unsigned short* __restrict__ khi, unsigned short* __restrict__ klo) {
    __shared__ unsigned short Ash[128*36], Asl[128*36], Bth[128*36], Btl[128*36];
    const int tid = threadIdx.x;
    const int n0 = blockIdx.x * 128;
    const int m0 = blockIdx.y * 128;
    const int lane = tid & 63, wid = tid >> 6;
    const int wm = wid >> 1, wn = wid & 1;
    const int lr = lane & 15, lc = lane >> 4;
    const int ar = tid >> 1, akc = (tid & 1) * 16;
    const int bk2 = (tid & 15) * 2, bnc = (tid >> 4) * 8;

    f32x4 acc[4][4];
    #pragma unroll
    for (int i = 0; i < 4; ++i)
        #pragma unroll
        for (int j = 0; j < 4; ++j) acc[i][j] = (f32x4){0.f, 0.f, 0.f, 0.f};

    for (int k0 = 0; k0 < D_MODEL; k0 += 32) {
        const float* ap = A + (size_t)(m0 + ar) * D_MODEL + k0 + akc;
        float4 a0 = *(const float4*)(ap);
        float4 a1 = *(const float4*)(ap + 4);
        float4 a2 = *(const float4*)(ap + 8);
        float4 a3 = *(const float4*)(ap + 12);
        const float* wp0 = Wm + (size_t)(k0 + bk2) * N3 + n0 + bnc;
        const float* wp1 = wp0 + N3;
        float4 w00 = *(const float4*)(wp0), w01 = *(const float4*)(wp0 + 4);
        float4 w10 = *(const float4*)(wp1), w11 = *(const float4*)(wp1 + 4);
        __syncthreads();
        {
            float af[16] = {a0.x,a0.y,a0.z,a0.w, a1.x,a1.y,a1.z,a1.w,
                            a2.x,a2.y,a2.z,a2.w, a3.x,a3.y,a3.z,a3.w};
            unsigned short hs[16], ls[16];
            #pragma unroll
            for (int i = 0; i < 16; ++i) {
                hs[i] = bf16_rne(af[i]);
                ls[i] = bf16_rne(af[i] - bf16_f(hs[i]));
            }
            #pragma unroll
            for (int i = 0; i < 16; i += 4) {
                *(ushort4*)&Ash[ar*36 + akc + i] = make_ushort4(hs[i],hs[i+1],hs[i+2],hs[i+3]);
                *(ushort4*)&Asl[ar*36 + akc + i] = make_ushort4(ls[i],ls[i+1],ls[i+2],ls[i+3]);
            }
            float r0[8] = {w00.x,w00.y,w00.z,w00.w, w01.x,w01.y,w01.z,w01.w};
            float r1[8] = {w10.x,w10.y,w10.z,w10.w, w11.x,w11.y,w11.z,w11.w};
            #pragma unroll
            for (int i = 0; i < 8; ++i) {
                unsigned short h0 = bf16_rne(r0[i]), h1 = bf16_rne(r1[i]);
                unsigned short l0 = bf16_rne(r0[i] - bf16_f(h0));
                unsigned short l1 = bf16_rne(r1[i] - bf16_f(h1));
                *(ushort2*)&Bth[(bnc + i)*36 + bk2] = make_ushort2(h0, h1);
                *(ushort2*)&Btl[(bnc + i)*36 + bk2] = make_ushort2(l0, l1);
            }
        }
        __syncthreads();
        bf16x8 ah[4], al[4], bh[4], bl[4];
        #pragma unroll
        for (int i = 0; i < 4; ++i) {
            int ra = (wm*64 + i*16 + lr)*36 + lc*8;
            int rb = (wn*64 + i*16 + lr)*36 + lc*8;
            ah[i] = *(const bf16x8*)&Ash[ra];
            al[i] = *(const bf16x8*)&Asl[ra];
            bh[i] = *(const bf16x8*)&Bth[rb];
            bl[i] = *(const bf16x8*)&Btl[rb];
        }
        #pragma unroll
        for (int mi = 0; mi < 4; ++mi)
            #pragma unroll
            for (int ni = 0; ni < 4; ++ni) {
                acc[mi][ni] = __builtin_amdgcn_mfma_f32_16x16x32_bf16(ah[mi], bh[ni], acc[mi][ni], 0, 0, 0);
                acc[mi][ni] = __builtin_amdgcn_mfma_f32_16x16x32_bf16(ah[mi], bl[ni], acc[mi][ni], 0, 0, 0);
                acc[mi][ni] = __builtin_amdgcn_mfma_f32_16x16x32_bf16(al[mi], bh[ni], acc[mi][ni], 0, 0, 0);
            }
    }
    #pragma unroll
    for (int ni = 0; ni < 4; ++ni) {
        int n = n0 + wn*64 + ni*16 + lr;
        float bv = bias[n];
        #pragma unroll
        for (int mi = 0; mi < 4; ++mi)
            #pragma unroll
            for (int r = 0; r < 4; ++r) {
                int m = m0 + wm*64 + mi*16 + lc*4 + r;
                float x = acc[mi][ni][r] + bv;
                unsigned short h = bf16_rne(x);
                khi[(size_t)m*2048 + n] = h;
                klo[(size_t)m*2048 + n] = bf16_rne(x - bf16_f(h));
            }
    }
}

// ============ GEMM-V: vt[n-2048][s] = (inputs @ W[:, 2048:3072] + b)^T, stored split ============
__global__ __launch_bounds__(256) void gemm_v(
        const float* __restrict__ A, const float* __restrict__ Wm,
        const float* __restrict__ bias,
        unsigned short* __restrict__ vthi, unsigned short* __restrict__ vtlo) {
    __shared__ unsigned short Ash[128*36], Asl[128*36], Bth[128*36], Btl[128*36];
    const int tid = threadIdx.x;
    const int n0 = 2048 + blockIdx.x * 128;
    const int m0 = blockIdx.y * 128;
    const int lane = tid & 63, wid = tid >> 6;
    const int wm = wid >> 1, wn = wid & 1;
    const int lr = lane & 15, lc = lane >> 4;
    const int ar = tid >> 1, akc = (tid & 1) * 16;
    const int bk2 = (tid & 15) * 2, bnc = (tid >> 4) * 8;

    f32x4 acc[4][4];
    #pragma unroll
    for (int i = 0; i < 4; ++i)
        #pragma unroll
        for (int j = 0; j < 4; ++j) acc[i][j] = (f32x4){0.f, 0.f, 0.f, 0.f};

    for (int k0 = 0; k0 < D_MODEL; k0 += 32) {
        const float* ap = A + (size_t)(m0 + ar) * D_MODEL + k0 + akc;
        float4 a0 = *(const float4*)(ap);
        float4 a1 = *(const float4*)(ap + 4);
        float4 a2 = *(const float4*)(ap + 8);
        float4 a3 = *(const float4*)(ap + 12);
        const float* wp0 = Wm + (size_t)(k0 + bk2) * N3 + n0 + bnc;
        const float* wp1 = wp0 + N3;
        float4 w00 = *(const float4*)(wp0), w01 = *(const float4*)(wp0 + 4);
        float4 w10 = *(const float4*)(wp1), w11 = *(const float4*)(wp1 + 4);
        __syncthreads();
        {
            float af[16] = {a0.x,a0.y,a0.z,a0.w, a1.x,a1.y,a1.z,a1.w,
                            a2.x,a2.y,a2.z,a2.w, a3.x,a3.y,a3.z,a3.w};
            unsigned short hs[16], ls[16];
            #pragma unroll
            for (int i = 0; i < 16; ++i) {
                hs[i] = bf16_rne(af[i]);
                ls[i] = bf16_rne(af[i] - bf16_f(hs[i]));
            }
            #pragma unroll
            for (int i = 0; i < 16; i += 4) {
                *(ushort4*)&Ash[ar*36 + akc + i] = make_ushort4(hs[i],hs[i+1],hs[i+2],hs[i+3]);
                *(ushort4*)&Asl[ar*36 + akc + i] = make_ushort4(ls[i],ls[i+1],ls[i+2],ls[i+3]);
            }
            float r0[8] = {w00.x,w00.y,w00.z,w00.w, w01.x,w01.y,w01.z,w01.w};
            float r1[8] = {w10.x,w10.y,w10.z,w10.w, w11.x,w11.y,w11.z,w11.w};
            #pragma unroll
            for (int i = 0; i < 8; ++i) {
                unsigned short h0 = bf16_rne(r0[i]), h1 = bf16_rne(r1[i]);
                unsigned short l0 = bf16_rne(r0[i] - bf16_f(h0));
                unsigned short l1 = bf16_rne(r1[i] - bf16_f(h1));
                *(ushort2*)&Bth[(bnc + i)*36 + bk2] = make_ushort2(h0, h1);
                *(ushort2*)&Btl[(bnc + i)*36 + bk2] = make_ushort2(l0, l1);
            }
        }
        __syncthreads();
        bf16x8 nh[4], nl[4], sh[4], sl[4];
        #pragma unroll
        for (int i = 0; i < 4; ++i) {
            int rb = (wm*64 + i*16 + lr)*36 + lc*8;   // n-side from W^T tile
            int ra = (wn*64 + i*16 + lr)*36 + lc*8;   // s-side from inputs tile
            nh[i] = *(const bf16x8*)&Bth[rb];
            nl[i] = *(const bf16x8*)&Btl[rb];
            sh[i] = *(const bf16x8*)&Ash[ra];
            sl[i] = *(const bf16x8*)&Asl[ra];
        }
        #pragma unroll
        for (int mi = 0; mi < 4; ++mi)
            #pragma unroll
            for (int ni = 0; ni < 4; ++ni) {
                acc[mi][ni] = __builtin_amdgcn_mfma_f32_16x16x32_bf16(nh[mi], sh[ni], acc[mi][ni], 0, 0, 0);
                acc[mi][ni] = __builtin_amdgcn_mfma_f32_16x16x32_bf16(nh[mi], sl[ni], acc[mi][ni], 0, 0, 0);
                acc[mi][ni] = __builtin_amdgcn_mfma_f32_16x16x32_bf16(nl[mi], sh[ni], acc[mi][ni], 0, 0, 0);
            }
    }
    #pragma unroll
    for (int mi = 0; mi < 4; ++mi)
        #pragma unroll
        for (int r = 0; r < 4; ++r) {
            int nr = n0 + wm*64 + mi*16 + lc*4 + r;   // global col in [2048,3072)
            float bv = bias[nr];
            int vrow = nr - 2048;
            #pragma unroll
            for (int ni = 0; ni < 4; ++ni) {
                int sg = m0 + wn*64 + ni*16 + lr;
                float x = acc[mi][ni][r] + bv;
                unsigned short h = bf16_rne(x);
                vthi[(size_t)vrow*4096 + sg] = h;
                vtlo[(size_t)vrow*4096 + sg] = bf16_rne(x - bf16_f(h));
            }
        }
}

// ============ Fused attention, k-split across waves, low-LDS quarter epilogue ============
// launch_bounds(256,2): VGPR cap 256 fits the ~250-reg live state (R9's (256,4)
// capped at 128 -> catastrophic scratch spill, 2 GB/dispatch HBM traffic).
#define NT 16   // 2048 / 128
__global__ __launch_bounds__(256, 2) void attn_mfma(
        const unsigned short* __restrict__ khi, const unsigned short* __restrict__ klo,
        const unsigned short* __restrict__ vthi, const unsigned short* __restrict__ vtlo,
        const float* __restrict__ masks, float* __restrict__ out) {
    __shared__ char pool[4*5120];             // 20480 B: per-wave Wt (k-loop) / acc quarter (epilogue)
    __shared__ float denL[4][64];
    unsigned short* Wt = (unsigned short*)pool;   // wave region: wid*2560 ushorts, [q][k] stride 40
    float* accL = (float*)pool;                   // wave region: wid*1280 floats, [q][d] stride 20

    const int tid = threadIdx.x;
    const int lane = tid & 63, wid = tid >> 6;
    const int lr = lane & 15, lc = lane >> 4;

    const int bid = blockIdx.x;
    const int work = (bid & 7) * 128 + (bid >> 3);   // XCD swizzle (1024 % 8 == 0, bijective)
    const int qb = work & 31;
    const int h  = (work >> 5) & 15;
    const int b  = work >> 9;
    const int q0 = qb * 64;
    const size_t srow = (size_t)b * S_LEN;

    // Q fragments (B-operand): q = q0+ni*16+lr, d = ks*32+lc*8, held all kernel
    bf16x8 qh[4][2], ql[4][2];
    #pragma unroll
    for (int ni = 0; ni < 4; ++ni)
        #pragma unroll
        for (int ks = 0; ks < 2; ++ks) {
            size_t off = (srow + q0 + ni*16 + lr) * 2048 + 1024 + h*64 + ks*32 + lc*8;
            qh[ni][ks] = *(const bf16x8*)(khi + off);
            ql[ni][ks] = *(const bf16x8*)(klo + off);
        }

    f32x4 acc[4][4];   // [ni: q-block][nd: d-block]
    #pragma unroll
    for (int i = 0; i < 4; ++i)
        #pragma unroll
        for (int j = 0; j < 4; ++j) acc[i][j] = (f32x4){0.f, 0.f, 0.f, 0.f};
    float den[4] = {0.f, 0.f, 0.f, 0.f};

    // K A-frags: rows = t*128 + wid*32 + mi*16 + lr, d = ks*32 + lc*8
    bf16x8 kh[2][2], kl[2][2];
    #pragma unroll
    for (int mi = 0; mi < 2; ++mi)
        #pragma unroll
        for (int ks = 0; ks < 2; ++ks) {
            size_t off = (srow + wid*32 + mi*16 + lr) * 2048 + h*64 + ks*32 + lc*8;
            kh[mi][ks] = *(const bf16x8*)(khi + off);
            kl[mi][ks] = *(const bf16x8*)(klo + off);
        }

    const int wtbase = wid * 2560;   // ushort index of this wave's Wt region

    for (int t = 0; t < NT; ++t) {
        // ---- QK^T (swapped: A=K slice, B=Q): u[mi][ni] reg r -> q=ni*16+lr, k=wid*32+mi*16+lc*4+r
        f32x4 u[2][4];
        #pragma unroll
        for (int mi = 0; mi < 2; ++mi)
            #pragma unroll
            for (int ni = 0; ni < 4; ++ni) u[mi][ni] = (f32x4){0.f, 0.f, 0.f, 0.f};
        #pragma unroll
        for (int ks = 0; ks < 2; ++ks)
            #pragma unroll
            for (int mi = 0; mi < 2; ++mi)
                #pragma unroll
                for (int ni = 0; ni < 4; ++ni) {
                    u[mi][ni] = __builtin_amdgcn_mfma_f32_16x16x32_bf16(kh[mi][ks], qh[ni][ks], u[mi][ni], 0, 0, 0);
                    u[mi][ni] = __builtin_amdgcn_mfma_f32_16x16x32_bf16(kh[mi][ks], ql[ni][ks], u[mi][ni], 0, 0, 0);
                    u[mi][ni] = __builtin_amdgcn_mfma_f32_16x16x32_bf16(kl[mi][ks], qh[ni][ks], u[mi][ni], 0, 0, 0);
                }
        // ---- prefetch next tile's K into the same frags (consumed next iteration)
        {
            int tn = (t + 1 < NT) ? t + 1 : t;
            #pragma unroll
            for (int mi = 0; mi < 2; ++mi)
                #pragma unroll
                for (int ks = 0; ks < 2; ++ks) {
                    size_t off = (srow + tn*128 + wid*32 + mi*16 + lr) * 2048 + h*64 + ks*32 + lc*8;
                    kh[mi][ks] = *(const bf16x8*)(khi + off);
                    kl[mi][ks] = *(const bf16x8*)(klo + off);
                }
        }
        // ---- V loads (issued early; consumed after exp)
        bf16x8 vh[4], vl[4];
        #pragma unroll
        for (int nd = 0; nd < 4; ++nd) {
            size_t voff = (size_t)(h*64 + nd*16 + lr) * 4096 + srow + t*128 + wid*32 + lc*8;
            vh[nd] = *(const bf16x8*)(vthi + voff);
            vl[nd] = *(const bf16x8*)(vtlo + voff);
        }
        // ---- masks for this lane's keys: k = t*128 + wid*32 + mi*16 + lc*4 + r
        float4 mk[2];
        #pragma unroll
        for (int mi = 0; mi < 2; ++mi)
            mk[mi] = *(const float4*)&masks[b*S_LEN + t*128 + wid*32 + mi*16 + lc*4];
        // ---- exp(elu-clip), pack to bf16 pairs, per-wave LDS transpose, den accum
        #pragma unroll
        for (int mi = 0; mi < 2; ++mi) {
            float mks[4] = {mk[mi].x, mk[mi].y, mk[mi].z, mk[mi].w};
            #pragma unroll
            for (int ni = 0; ni < 4; ++ni) {
                #pragma unroll
                for (int p = 0; p < 2; ++p) {
                    float x0 = u[mi][ni][2*p],   x1 = u[mi][ni][2*p+1];
                    float e0 = __expf(fminf(x0, 0.f)), e1 = __expf(fminf(x1, 0.f));
                    float t0 = x0 > 0.f ? x0 : e0 - 1.f;
                    float t1 = x1 > 0.f ? x1 : e1 - 1.f;
                    t0 = fminf(t0, 10.f); t1 = fminf(t1, 10.f);
                    float w0 = __expf(t0) * mks[2*p];
                    float w1 = __expf(t1) * mks[2*p+1];
                    unsigned short b0 = bf16_rne(w0), b1 = bf16_rne(w1);
                    den[ni] += bf16_f(b0) + bf16_f(b1);
                    unsigned int packed = (unsigned int)b0 | ((unsigned int)b1 << 16);
                    // Wt[q][k]: q = ni*16+lr (stride 40), k = mi*16 + lc*4 + 2p
                    *(unsigned int*)&Wt[wtbase + (ni*16 + lr)*40 + mi*16 + lc*4 + 2*p] = packed;
                }
            }
        }
        // ---- PV: A = P[q=lr][k=lc*8..+8] from Wt, B = V frags; acc[ni][nd]
        #pragma unroll
        for (int ni = 0; ni < 4; ++ni) {
            bf16x8 pa = *(const bf16x8*)&Wt[wtbase + (ni*16 + lr)*40 + lc*8];
            #pragma unroll
            for (int nd = 0; nd < 4; ++nd) {
                acc[ni][nd] = __builtin_amdgcn_mfma_f32_16x16x32_bf16(pa, vh[nd], acc[ni][nd], 0, 0, 0);
                acc[ni][nd] = __builtin_amdgcn_mfma_f32_16x16x32_bf16(pa, vl[nd], acc[ni][nd], 0, 0, 0);
            }
        }
    }

    // ---- den: reduce across lc groups (same q, different k subsets)
    #pragma unroll
    for (int ni = 0; ni < 4; ++ni) {
        float d = den[ni];
        d += __shfl_xor(d, 16);
        d += __shfl_xor(d, 32);
        den[ni] = d;
    }
    if (lc == 0) {
        #pragma unroll
        for (int ni = 0; ni < 4; ++ni) denL[wid][ni*16 + lr] = den[ni];
    }
    // ---- quarter-wise cross-wave reduction: per-wave accL region overlays own Wt region
    const int q  = tid >> 2;            // 0..63
    const int dg = (tid & 3) * 4;       // 0,4,8,12 within the 16-wide quarter
    float scale = 0.f;
    float* my = accL + wid * 1280;      // [64][20] floats
    #pragma unroll
    for (int nd = 0; nd < 4; ++nd) {
        #pragma unroll
        for (int ni = 0; ni < 4; ++ni)
            #pragma unroll
            for (int r = 0; r < 4; ++r)
                my[(ni*16 + lc*4 + r)*20 + lr] = acc[ni][nd][r];
        __syncthreads();
        if (nd == 0) {
            float dsum = denL[0][q] + denL[1][q] + denL[2][q] + denL[3][q];
            scale = masks[b*S_LEN + q0 + q] / dsum;
        }
        float4 s0 = *(float4*)&accL[0*1280 + q*20 + dg];
        float4 s1 = *(float4*)&accL[1*1280 + q*20 + dg];
        float4 s2 = *(float4*)&accL[2*1280 + q*20 + dg];
        float4 s3 = *(float4*)&accL[3*1280 + q*20 + dg];
        float4 o = make_float4((s0.x+s1.x+s2.x+s3.x)*scale,
                               (s0.y+s1.y+s2.y+s3.y)*scale,
                               (s0.z+s1.z+s2.z+s3.z)*scale,
                               (s0.w+s1.w+s2.w+s3.w)*scale);
        *(float4*)&out[(srow + q0 + q)*D_MODEL + h*64 + nd*16 + dg] = o;
        __syncthreads();
    }
}

extern "C" void kernel_launch(void* const* d_in, const int* in_sizes, int n_in,
                              void* d_out, int out_size, void* d_ws, size_t ws_size,
                              hipStream_t stream) {
    (void)in_sizes; (void)n_in; (void)out_size; (void)ws_size;
    const float* inputs = (const float*)d_in[0];
    const float* masks  = (const float*)d_in[1];
    const float* Wm     = (const float*)d_in[2];
    const float* bias   = (const float*)d_in[3];
    float* outp = (float*)d_out;

    // ws layout (50,331,648 B):
    unsigned short* khi  = (unsigned short*)d_ws;
    unsigned short* klo  = khi + (size_t)4096*2048;
    unsigned short* vthi = klo + (size_t)4096*2048;
    unsigned short* vtlo = vthi + (size_t)1024*4096;

    gemm_kq<<<dim3(16, 32), 256, 0, stream>>>(inputs, Wm, bias, khi, klo);
    gemm_v <<<dim3(8, 32), 256, 0, stream>>>(inputs, Wm, bias, vthi, vtlo);
    attn_mfma<<<1024, 256, 0, stream>>>(khi, klo, vthi, vtlo, masks, outp);
}

// Round 13
// 297.606 us; speedup vs baseline: 2.3686x; 1.1729x over previous
//
#include <hip/hip_runtime.h>

#define S_LEN 2048
#define D_MODEL 1024
#define N3 3072
#define NHEAD 16
#define DHEAD 64

typedef __attribute__((ext_vector_type(8))) short bf16x8;
typedef __attribute__((ext_vector_type(4))) float f32x4;

__device__ __forceinline__ unsigned short bf16_rne(float x) {
    unsigned int u = __float_as_uint(x);
    u += 0x7FFFu + ((u >> 16) & 1u);
    return (unsigned short)(u >> 16);
}
__device__ __forceinline__ float bf16_f(unsigned short h) {
    return __uint_as_float(((unsigned int)h) << 16);
}

// ============ GEMM-KQ: C[:, 0:2048] = inputs @ W[:, 0:2048] + b, SINGLE bf16 ============
// Q/K feed QK^T whose rounding error cancels in the softmax normalization
// (common-mode). 1-term MFMA, rne-only conversion, half the LDS.
__global__ __launch_bounds__(256) void gemm_kq(
        const float* __restrict__ A, const float* __restrict__ Wm,
        const float* __restrict__ bias,
        unsigned short* __restrict__ khi) {
    __shared__ unsigned short Ash[128*36], Bth[128*36];
    const int tid = threadIdx.x;
    const int n0 = blockIdx.x * 128;
    const int m0 = blockIdx.y * 128;
    const int lane = tid & 63, wid = tid >> 6;
    const int wm = wid >> 1, wn = wid & 1;
    const int lr = lane & 15, lc = lane >> 4;
    const int ar = tid >> 1, akc = (tid & 1) * 16;
    const int bk2 = (tid & 15) * 2, bnc = (tid >> 4) * 8;

    f32x4 acc[4][4];
    #pragma unroll
    for (int i = 0; i < 4; ++i)
        #pragma unroll
        for (int j = 0; j < 4; ++j) acc[i][j] = (f32x4){0.f, 0.f, 0.f, 0.f};

    for (int k0 = 0; k0 < D_MODEL; k0 += 32) {
        const float* ap = A + (size_t)(m0 + ar) * D_MODEL + k0 + akc;
        float4 a0 = *(const float4*)(ap);
        float4 a1 = *(const float4*)(ap + 4);
        float4 a2 = *(const float4*)(ap + 8);
        float4 a3 = *(const float4*)(ap + 12);
        const float* wp0 = Wm + (size_t)(k0 + bk2) * N3 + n0 + bnc;
        const float* wp1 = wp0 + N3;
        float4 w00 = *(const float4*)(wp0), w01 = *(const float4*)(wp0 + 4);
        float4 w10 = *(const float4*)(wp1), w11 = *(const float4*)(wp1 + 4);
        __syncthreads();
        {
            float af[16] = {a0.x,a0.y,a0.z,a0.w, a1.x,a1.y,a1.z,a1.w,
                            a2.x,a2.y,a2.z,a2.w, a3.x,a3.y,a3.z,a3.w};
            unsigned short hs[16];
            #pragma unroll
            for (int i = 0; i < 16; ++i) hs[i] = bf16_rne(af[i]);
            #pragma unroll
            for (int i = 0; i < 16; i += 4)
                *(ushort4*)&Ash[ar*36 + akc + i] = make_ushort4(hs[i],hs[i+1],hs[i+2],hs[i+3]);
            float r0[8] = {w00.x,w00.y,w00.z,w00.w, w01.x,w01.y,w01.z,w01.w};
            float r1[8] = {w10.x,w10.y,w10.z,w10.w, w11.x,w11.y,w11.z,w11.w};
            #pragma unroll
            for (int i = 0; i < 8; ++i)
                *(ushort2*)&Bth[(bnc + i)*36 + bk2] = make_ushort2(bf16_rne(r0[i]), bf16_rne(r1[i]));
        }
        __syncthreads();
        bf16x8 ah[4], bh[4];
        #pragma unroll
        for (int i = 0; i < 4; ++i) {
            ah[i] = *(const bf16x8*)&Ash[(wm*64 + i*16 + lr)*36 + lc*8];
            bh[i] = *(const bf16x8*)&Bth[(wn*64 + i*16 + lr)*36 + lc*8];
        }
        #pragma unroll
        for (int mi = 0; mi < 4; ++mi)
            #pragma unroll
            for (int ni = 0; ni < 4; ++ni)
                acc[mi][ni] = __builtin_amdgcn_mfma_f32_16x16x32_bf16(ah[mi], bh[ni], acc[mi][ni], 0, 0, 0);
    }
    #pragma unroll
    for (int ni = 0; ni < 4; ++ni) {
        int n = n0 + wn*64 + ni*16 + lr;
        float bv = bias[n];
        #pragma unroll
        for (int mi = 0; mi < 4; ++mi)
            #pragma unroll
            for (int r = 0; r < 4; ++r) {
                int m = m0 + wm*64 + mi*16 + lc*4 + r;
                khi[(size_t)m*2048 + n] = bf16_rne(acc[mi][ni][r] + bv);
            }
    }
}

// ============ GEMM-V: vt[n-2048][s] = (inputs @ W[:, 2048:3072] + b)^T, stored split ============
// V errors pass straight to the output -> keep hi/lo split (3-term MFMA).
__global__ __launch_bounds__(256) void gemm_v(
        const float* __restrict__ A, const float* __restrict__ Wm,
        const float* __restrict__ bias,
        unsigned short* __restrict__ vthi, unsigned short* __restrict__ vtlo) {
    __shared__ unsigned short Ash[128*36], Asl[128*36], Bth[128*36], Btl[128*36];
    const int tid = threadIdx.x;
    const int n0 = 2048 + blockIdx.x * 128;
    const int m0 = blockIdx.y * 128;
    const int lane = tid & 63, wid = tid >> 6;
    const int wm = wid >> 1, wn = wid & 1;
    const int lr = lane & 15, lc = lane >> 4;
    const int ar = tid >> 1, akc = (tid & 1) * 16;
    const int bk2 = (tid & 15) * 2, bnc = (tid >> 4) * 8;

    f32x4 acc[4][4];
    #pragma unroll
    for (int i = 0; i < 4; ++i)
        #pragma unroll
        for (int j = 0; j < 4; ++j) acc[i][j] = (f32x4){0.f, 0.f, 0.f, 0.f};

    for (int k0 = 0; k0 < D_MODEL; k0 += 32) {
        const float* ap = A + (size_t)(m0 + ar) * D_MODEL + k0 + akc;
        float4 a0 = *(const float4*)(ap);
        float4 a1 = *(const float4*)(ap + 4);
        float4 a2 = *(const float4*)(ap + 8);
        float4 a3 = *(const float4*)(ap + 12);
        const float* wp0 = Wm + (size_t)(k0 + bk2) * N3 + n0 + bnc;
        const float* wp1 = wp0 + N3;
        float4 w00 = *(const float4*)(wp0), w01 = *(const float4*)(wp0 + 4);
        float4 w10 = *(const float4*)(wp1), w11 = *(const float4*)(wp1 + 4);
        __syncthreads();
        {
            float af[16] = {a0.x,a0.y,a0.z,a0.w, a1.x,a1.y,a1.z,a1.w,
                            a2.x,a2.y,a2.z,a2.w, a3.x,a3.y,a3.z,a3.w};
            unsigned short hs[16], ls[16];
            #pragma unroll
            for (int i = 0; i < 16; ++i) {
                hs[i] = bf16_rne(af[i]);
                ls[i] = bf16_rne(af[i] - bf16_f(hs[i]));
            }
            #pragma unroll
            for (int i = 0; i < 16; i += 4) {
                *(ushort4*)&Ash[ar*36 + akc + i] = make_ushort4(hs[i],hs[i+1],hs[i+2],hs[i+3]);
                *(ushort4*)&Asl[ar*36 + akc + i] = make_ushort4(ls[i],ls[i+1],ls[i+2],ls[i+3]);
            }
            float r0[8] = {w00.x,w00.y,w00.z,w00.w, w01.x,w01.y,w01.z,w01.w};
            float r1[8] = {w10.x,w10.y,w10.z,w10.w, w11.x,w11.y,w11.z,w11.w};
            #pragma unroll
            for (int i = 0; i < 8; ++i) {
                unsigned short h0 = bf16_rne(r0[i]), h1 = bf16_rne(r1[i]);
                unsigned short l0 = bf16_rne(r0[i] - bf16_f(h0));
                unsigned short l1 = bf16_rne(r1[i] - bf16_f(h1));
                *(ushort2*)&Bth[(bnc + i)*36 + bk2] = make_ushort2(h0, h1);
                *(ushort2*)&Btl[(bnc + i)*36 + bk2] = make_ushort2(l0, l1);
            }
        }
        __syncthreads();
        bf16x8 nh[4], nl[4], sh[4], sl[4];
        #pragma unroll
        for (int i = 0; i < 4; ++i) {
            int rb = (wm*64 + i*16 + lr)*36 + lc*8;   // n-side from W^T tile
            int ra = (wn*64 + i*16 + lr)*36 + lc*8;   // s-side from inputs tile
            nh[i] = *(const bf16x8*)&Bth[rb];
            nl[i] = *(const bf16x8*)&Btl[rb];
            sh[i] = *(const bf16x8*)&Ash[ra];
            sl[i] = *(const bf16x8*)&Asl[ra];
        }
        #pragma unroll
        for (int mi = 0; mi < 4; ++mi)
            #pragma unroll
            for (int ni = 0; ni < 4; ++ni) {
                acc[mi][ni] = __builtin_amdgcn_mfma_f32_16x16x32_bf16(nh[mi], sh[ni], acc[mi][ni], 0, 0, 0);
                acc[mi][ni] = __builtin_amdgcn_mfma_f32_16x16x32_bf16(nh[mi], sl[ni], acc[mi][ni], 0, 0, 0);
                acc[mi][ni] = __builtin_amdgcn_mfma_f32_16x16x32_bf16(nl[mi], sh[ni], acc[mi][ni], 0, 0, 0);
            }
    }
    #pragma unroll
    for (int mi = 0; mi < 4; ++mi)
        #pragma unroll
        for (int r = 0; r < 4; ++r) {
            int nr = n0 + wm*64 + mi*16 + lc*4 + r;   // global col in [2048,3072)
            float bv = bias[nr];
            int vrow = nr - 2048;
            #pragma unroll
            for (int ni = 0; ni < 4; ++ni) {
                int sg = m0 + wn*64 + ni*16 + lr;
                float x = acc[mi][ni][r] + bv;
                unsigned short h = bf16_rne(x);
                vthi[(size_t)vrow*4096 + sg] = h;
                vtlo[(size_t)vrow*4096 + sg] = bf16_rne(x - bf16_f(h));
            }
        }
}

// ============ Fused attention: single-bf16 QK^T (1 MFMA term), split-V PV ============
#define NT 16   // 2048 / 128
__global__ __launch_bounds__(256, 2) void attn_mfma(
        const unsigned short* __restrict__ khi,
        const unsigned short* __restrict__ vthi, const unsigned short* __restrict__ vtlo,
        const float* __restrict__ masks, float* __restrict__ out) {
    __shared__ char pool[4*5120];             // per-wave Wt (k-loop) / acc quarter (epilogue)
    __shared__ float denL[4][64];
    unsigned short* Wt = (unsigned short*)pool;
    float* accL = (float*)pool;

    const int tid = threadIdx.x;
    const int lane = tid & 63, wid = tid >> 6;
    const int lr = lane & 15, lc = lane >> 4;

    const int bid = blockIdx.x;
    const int work = (bid & 7) * 128 + (bid >> 3);   // XCD swizzle (bijective, 1024%8==0)
    const int qb = work & 31;
    const int h  = (work >> 5) & 15;
    const int b  = work >> 9;
    const int q0 = qb * 64;
    const size_t srow = (size_t)b * S_LEN;

    // Q fragments (B-operand), single bf16: q = q0+ni*16+lr, d = ks*32+lc*8
    bf16x8 qh[4][2];
    #pragma unroll
    for (int ni = 0; ni < 4; ++ni)
        #pragma unroll
        for (int ks = 0; ks < 2; ++ks)
            qh[ni][ks] = *(const bf16x8*)(khi + (srow + q0 + ni*16 + lr) * 2048 + 1024 + h*64 + ks*32 + lc*8);

    f32x4 acc[4][4];   // [ni: q-block][nd: d-block]
    #pragma unroll
    for (int i = 0; i < 4; ++i)
        #pragma unroll
        for (int j = 0; j < 4; ++j) acc[i][j] = (f32x4){0.f, 0.f, 0.f, 0.f};
    float den[4] = {0.f, 0.f, 0.f, 0.f};

    // K A-frags, single bf16: rows = t*128 + wid*32 + mi*16 + lr, d = ks*32 + lc*8
    bf16x8 kh[2][2];
    #pragma unroll
    for (int mi = 0; mi < 2; ++mi)
        #pragma unroll
        for (int ks = 0; ks < 2; ++ks)
            kh[mi][ks] = *(const bf16x8*)(khi + (srow + wid*32 + mi*16 + lr) * 2048 + h*64 + ks*32 + lc*8);

    const int wtbase = wid * 2560;

    for (int t = 0; t < NT; ++t) {
        // ---- QK^T (swapped: A=K slice, B=Q), 1 term
        f32x4 u[2][4];
        #pragma unroll
        for (int mi = 0; mi < 2; ++mi)
            #pragma unroll
            for (int ni = 0; ni < 4; ++ni) u[mi][ni] = (f32x4){0.f, 0.f, 0.f, 0.f};
        #pragma unroll
        for (int ks = 0; ks < 2; ++ks)
            #pragma unroll
            for (int mi = 0; mi < 2; ++mi)
                #pragma unroll
                for (int ni = 0; ni < 4; ++ni)
                    u[mi][ni] = __builtin_amdgcn_mfma_f32_16x16x32_bf16(kh[mi][ks], qh[ni][ks], u[mi][ni], 0, 0, 0);
        // ---- prefetch next tile's K
        {
            int tn = (t + 1 < NT) ? t + 1 : t;
            #pragma unroll
            for (int mi = 0; mi < 2; ++mi)
                #pragma unroll
                for (int ks = 0; ks < 2; ++ks)
                    kh[mi][ks] = *(const bf16x8*)(khi + (srow + tn*128 + wid*32 + mi*16 + lr) * 2048 + h*64 + ks*32 + lc*8);
        }
        // ---- V loads (split hi/lo)
        bf16x8 vh[4], vl[4];
        #pragma unroll
        for (int nd = 0; nd < 4; ++nd) {
            size_t voff = (size_t)(h*64 + nd*16 + lr) * 4096 + srow + t*128 + wid*32 + lc*8;
            vh[nd] = *(const bf16x8*)(vthi + voff);
            vl[nd] = *(const bf16x8*)(vtlo + voff);
        }
        // ---- masks for this lane's keys
        float4 mk[2];
        #pragma unroll
        for (int mi = 0; mi < 2; ++mi)
            mk[mi] = *(const float4*)&masks[b*S_LEN + t*128 + wid*32 + mi*16 + lc*4];
        // ---- exp(elu-clip), pack bf16, per-wave LDS transpose, den accum
        #pragma unroll
        for (int mi = 0; mi < 2; ++mi) {
            float mks[4] = {mk[mi].x, mk[mi].y, mk[mi].z, mk[mi].w};
            #pragma unroll
            for (int ni = 0; ni < 4; ++ni) {
                #pragma unroll
                for (int p = 0; p < 2; ++p) {
                    float x0 = u[mi][ni][2*p],   x1 = u[mi][ni][2*p+1];
                    float e0 = __expf(fminf(x0, 0.f)), e1 = __expf(fminf(x1, 0.f));
                    float t0 = x0 > 0.f ? x0 : e0 - 1.f;
                    float t1 = x1 > 0.f ? x1 : e1 - 1.f;
                    t0 = fminf(t0, 10.f); t1 = fminf(t1, 10.f);
                    float w0 = __expf(t0) * mks[2*p];
                    float w1 = __expf(t1) * mks[2*p+1];
                    unsigned short b0 = bf16_rne(w0), b1 = bf16_rne(w1);
                    den[ni] += bf16_f(b0) + bf16_f(b1);
                    unsigned int packed = (unsigned int)b0 | ((unsigned int)b1 << 16);
                    *(unsigned int*)&Wt[wtbase + (ni*16 + lr)*40 + mi*16 + lc*4 + 2*p] = packed;
                }
            }
        }
        // ---- PV: A = P from Wt, B = V hi/lo
        #pragma unroll
        for (int ni = 0; ni < 4; ++ni) {
            bf16x8 pa = *(const bf16x8*)&Wt[wtbase + (ni*16 + lr)*40 + lc*8];
            #pragma unroll
            for (int nd = 0; nd < 4; ++nd) {
                acc[ni][nd] = __builtin_amdgcn_mfma_f32_16x16x32_bf16(pa, vh[nd], acc[ni][nd], 0, 0, 0);
                acc[ni][nd] = __builtin_amdgcn_mfma_f32_16x16x32_bf16(pa, vl[nd], acc[ni][nd], 0, 0, 0);
            }
        }
    }

    // ---- den: reduce across lc groups
    #pragma unroll
    for (int ni = 0; ni < 4; ++ni) {
        float d = den[ni];
        d += __shfl_xor(d, 16);
        d += __shfl_xor(d, 32);
        den[ni] = d;
    }
    if (lc == 0) {
        #pragma unroll
        for (int ni = 0; ni < 4; ++ni) denL[wid][ni*16 + lr] = den[ni];
    }
    // ---- quarter-wise cross-wave reduction (per-wave accL overlays own Wt region)
    const int q  = tid >> 2;
    const int dg = (tid & 3) * 4;
    float scale = 0.f;
    float* my = accL + wid * 1280;
    #pragma unroll
    for (int nd = 0; nd < 4; ++nd) {
        #pragma unroll
        for (int ni = 0; ni < 4; ++ni)
            #pragma unroll
            for (int r = 0; r < 4; ++r)
                my[(ni*16 + lc*4 + r)*20 + lr] = acc[ni][nd][r];
        __syncthreads();
        if (nd == 0) {
            float dsum = denL[0][q] + denL[1][q] + denL[2][q] + denL[3][q];
            scale = masks[b*S_LEN + q0 + q] / dsum;
        }
        float4 s0 = *(float4*)&accL[0*1280 + q*20 + dg];
        float4 s1 = *(float4*)&accL[1*1280 + q*20 + dg];
        float4 s2 = *(float4*)&accL[2*1280 + q*20 + dg];
        float4 s3 = *(float4*)&accL[3*1280 + q*20 + dg];
        float4 o = make_float4((s0.x+s1.x+s2.x+s3.x)*scale,
                               (s0.y+s1.y+s2.y+s3.y)*scale,
                               (s0.z+s1.z+s2.z+s3.z)*scale,
                               (s0.w+s1.w+s2.w+s3.w)*scale);
        *(float4*)&out[(srow + q0 + q)*D_MODEL + h*64 + nd*16 + dg] = o;
        __syncthreads();
    }
}

extern "C" void kernel_launch(void* const* d_in, const int* in_sizes, int n_in,
                              void* d_out, int out_size, void* d_ws, size_t ws_size,
                              hipStream_t stream) {
    (void)in_sizes; (void)n_in; (void)out_size; (void)ws_size;
    const float* inputs = (const float*)d_in[0];
    const float* masks  = (const float*)d_in[1];
    const float* Wm     = (const float*)d_in[2];
    const float* bias   = (const float*)d_in[3];
    float* outp = (float*)d_out;

    // ws layout (same 50,331,648 B footprint; klo region now unused):
    unsigned short* khi  = (unsigned short*)d_ws;
    unsigned short* klo  = khi + (size_t)4096*2048;  (void)klo;
    unsigned short* vthi = klo + (size_t)4096*2048;
    unsigned short* vtlo = vthi + (size_t)1024*4096;

    gemm_kq<<<dim3(16, 32), 256, 0, stream>>>(inputs, Wm, bias, khi);
    gemm_v <<<dim3(8, 32), 256, 0, stream>>>(inputs, Wm, bias, vthi, vtlo);
    attn_mfma<<<1024, 256, 0, stream>>>(khi, vthi, vtlo, masks, outp);
}